// Round 2
// baseline (239.362 us; speedup 1.0000x reference)
//
#include <hip/hip_runtime.h>

// Xonv2D: location-dependent 3x3 conv.
//   x:       (B=4, CIN=16, H=128, W=128)  fp32   -- 4 MB, L2/L3-resident
//   weights: (H, W, COUT=16, CIN=16, 3, 3) fp32  -- 151 MB, the traffic driver
//   bias:    (H, W, COUT) fp32
//   out:     (B, COUT, H, W) fp32
//
// V7: fix V6's vmcnt interference; counted waits; persistent 8-site waves.
//  V6's depth-1 prefetch was issued at the TOP of the iteration, before the
//  compute's x-loads. vmcnt is one in-order counter: the compiler's waits
//  for x-load results had to drain the older weight prefetch first, so the
//  prefetch completed at the first fma -- no overlap, plus halved occupancy
//  (128thr blocks). V7 issues the next site's 9 global_load_lds at the END
//  of the compute phase (after every x-load in program order, pinned with
//  sched_barrier + "memory" asm), so:
//    - x-load waits (newer than nothing relevant) never touch the prefetch;
//    - the prefetch flies across store + loop-branch + the NEXT iteration's
//      counted wait, i.e. a full compute phase (~600cy) plus the wait window.
//  Iteration top waits vmcnt(9): all but the newest burst (next buffer)
//  complete -- T4 discipline, never vmcnt(0) in the steady loop (only the
//  final iteration drains). Per-wave load flow becomes continuous (~90%
//  duty) instead of bursty (~50%), with 8 waves/CU x ~9KB in flight.
//
//  Grid: 512 blocks x 256 thr, 72KB LDS (4 waves x 2 bufs x 9216B) -> 2
//  blocks/CU, exactly 512 resident: single round, persistent, no relaunch.
//  Each wave streams 8 consecutive sites = 72KB contiguous weights.
//  Weight path no longer uses nontemporal loads (suspect for the BW gap);
//  global_load_lds also deletes the ds_writes + 36 staging VGPRs of v5.
//
// Kept: coalesced weight order (lane l takes f4 j*64+l, linear LDS dest --
// the only layout global_load_lds supports), per-lane (o,g) 36-float
// fragment via ds_read_b128, x rows as dword-aligned float4 with w<=125
// fast path, wave-uniform border path, XCD banding, butterfly reduce,
// single store per lane.

#define HWD   128
#define CIND  16
#define COUTD 16
#define BATCH 4
#define SPW   8     // sites per wave (consecutive, same row: site0 % 8 == 0)
#define WPB   4     // waves per block

typedef float f4  __attribute__((ext_vector_type(4)));
typedef float f4u __attribute__((ext_vector_type(4), aligned(4)));

// async DMA: 16B per lane, LDS dest = wave-uniform base + lane*16 (linear).
__device__ __forceinline__ void gload_lds16(const f4* gsrc, f4* ldst) {
    __builtin_amdgcn_global_load_lds(
        (const __attribute__((address_space(1))) unsigned int*)gsrc,
        (__attribute__((address_space(3))) unsigned int*)ldst,
        16, 0, 0);
}

__global__ __launch_bounds__(256) void xonv2d_kernel(
    const float* __restrict__ x,
    const float* __restrict__ wts,
    const float* __restrict__ bias,
    float* __restrict__ out)
{
    __shared__ f4 wsm[WPB][2][576];   // 4 waves x 2 buffers x 9216 B = 72 KB

    const int lane = threadIdx.x & 63;
    const int wave = threadIdx.x >> 6;

    // XCD banding: XCD k = blockIdx%8 handles sites [k*2048, (k+1)*2048).
    const int xcd = blockIdx.x & 7;
    const int idx = blockIdx.x >> 3;                    // 0..63 within band
    const int site0 = xcd * 2048 + (idx * WPB + wave) * SPW;

    const int o  = lane & 15;    // output channel
    const int g  = lane >> 4;    // channel group: c in [4g, 4g+4)
    const int c0 = g * 4;

    // ---- prologue: DMA sites 0 and 1 into buffers 0 and 1 ----
    {
        const f4* gw = (const f4*)wts + (size_t)site0 * 576;
        #pragma unroll
        for (int j = 0; j < 9; ++j)
            gload_lds16(gw + j * 64 + lane, &wsm[wave][0][j * 64]);
        gw += 576;
        #pragma unroll
        for (int j = 0; j < 9; ++j)
            gload_lds16(gw + j * 64 + lane, &wsm[wave][1][j * 64]);
    }

    #pragma unroll 1
    for (int s = 0; s < SPW; ++s) {
        const int site = site0 + s;
        const int h = site >> 7;
        const int w = site & 127;

        // Counted wait: all but the newest 9 (the in-flight next buffer)
        // are complete -> buffer s&1 is ready. Only the last iteration
        // (no newer burst exists) drains to 0.
        if (s < SPW - 1) asm volatile("s_waitcnt vmcnt(9)" ::: "memory");
        else             asm volatile("s_waitcnt vmcnt(0)" ::: "memory");

        // bias: one dword load, consumed only at the store
        const float bv = bias[(size_t)site * COUTD + o];

        // ---- per-lane (o,g) 36-float fragment via ds_read_b128 ----
        f4 wv[9];
        {
            const f4* lp = &wsm[wave][s & 1][o * 36 + g * 9];
            #pragma unroll
            for (int j = 0; j < 9; ++j) wv[j] = lp[j];
        }
        const float* wf = (const float*)wv;

        float acc[BATCH] = {0.f, 0.f, 0.f, 0.f};

        // w <= 125: float4 row loads read cols w-1..w+2 <= 127, in-bounds.
        const bool interior = (h >= 1) & (h <= HWD - 2) & (w >= 1) & (w <= HWD - 3);

        if (interior) {
            #pragma unroll
            for (int cc = 0; cc < 4; ++cc) {
                #pragma unroll
                for (int b = 0; b < BATCH; ++b) {
                    const float* xb = x + (((size_t)(b * CIND + c0 + cc) * HWD + (h - 1)) * HWD) + (w - 1);
                    f4 r0 = *(const f4u*)(xb);
                    f4 r1 = *(const f4u*)(xb + HWD);
                    f4 r2 = *(const f4u*)(xb + 2 * HWD);
                    const float* wr = wf + cc * 9;
                    acc[b] = fmaf(r0.x, wr[0], acc[b]);
                    acc[b] = fmaf(r0.y, wr[1], acc[b]);
                    acc[b] = fmaf(r0.z, wr[2], acc[b]);
                    acc[b] = fmaf(r1.x, wr[3], acc[b]);
                    acc[b] = fmaf(r1.y, wr[4], acc[b]);
                    acc[b] = fmaf(r1.z, wr[5], acc[b]);
                    acc[b] = fmaf(r2.x, wr[6], acc[b]);
                    acc[b] = fmaf(r2.y, wr[7], acc[b]);
                    acc[b] = fmaf(r2.z, wr[8], acc[b]);
                }
            }
        } else {
            #pragma unroll
            for (int cc = 0; cc < 4; ++cc) {
                #pragma unroll
                for (int b = 0; b < BATCH; ++b) {
                    const float* xb = x + ((size_t)(b * CIND + c0 + cc)) * (HWD * HWD);
                    #pragma unroll
                    for (int kh = 0; kh < 3; ++kh) {
                        const int hy = h + kh - 1;
                        #pragma unroll
                        for (int kw = 0; kw < 3; ++kw) {
                            const int wx = w + kw - 1;
                            const bool ok = (hy >= 0) & (hy < HWD) & (wx >= 0) & (wx < HWD);
                            const float xv = ok ? xb[hy * HWD + wx] : 0.f;
                            acc[b] = fmaf(xv, wf[cc * 9 + kh * 3 + kw], acc[b]);
                        }
                    }
                }
            }
        }

        // ---- butterfly reduce over the 4 c-groups ----
        float r[BATCH];
        #pragma unroll
        for (int b = 0; b < BATCH; ++b) {
            float v = acc[b];
            v += __shfl_xor(v, 32);
            v += __shfl_xor(v, 16);
            r[b] = v;
        }

        // lane (g,o) stores batch b = g: one store, all 64 lanes active
        const float vout = (g == 0) ? r[0] : (g == 1) ? r[1] : (g == 2) ? r[2] : r[3];
        out[((size_t)(g * COUTD + o)) * (HWD * HWD) + h * HWD + w] = vout + bv;

        // ---- issue the NEXT prefetch LAST: after every x-load in program
        // order, so x-load waits never drain it (in-order vmcnt). It flies
        // across store + branch + next iteration's counted wait. ----
        if (s + 2 < SPW) {
            __builtin_amdgcn_sched_barrier(0);
            const f4* gw = (const f4*)wts + (size_t)(site + 2) * 576;
            #pragma unroll
            for (int j = 0; j < 9; ++j)
                gload_lds16(gw + j * 64 + lane, &wsm[wave][s & 1][j * 64]);
            __builtin_amdgcn_sched_barrier(0);
        }
    }
}

extern "C" void kernel_launch(void* const* d_in, const int* in_sizes, int n_in,
                              void* d_out, int out_size, void* d_ws, size_t ws_size,
                              hipStream_t stream) {
    const float* x    = (const float*)d_in[0];
    const float* wts  = (const float*)d_in[1];
    const float* bias = (const float*)d_in[2];
    float* out = (float*)d_out;

    // 16384 sites / (4 waves * 8 sites) = 512 blocks of 256 threads.
    // 72KB LDS -> 2 blocks/CU, exactly 512 resident: persistent, no rounds.
    const int blocks = (HWD * HWD) / (WPB * SPW);
    xonv2d_kernel<<<blocks, WPB * 64, 0, stream>>>(x, wts, bias, out);
}